// Round 1
// baseline (120.518 us; speedup 1.0000x reference)
//
#include <hip/hip_runtime.h>

// Problem: 14-step recurrence. Each step t (t=0..13):
//   temp = J @ r_{t-1}            (N=1680, fp32, row-major J)
//   U    = temp + Iext
//   sq   = (0.2*U)^2
//   recSum = 0.005 * sum(sq)
//   r_t  = sq / recSum
// Outputs (fp32, flat): U_13 (1680), recSum_13 (1), r_13 (1680)
//
// Trick: carry unnormalized r̃_t = sq_t and scalar s_t = recSum_t.
//   J @ r_{t-1} = (J @ r̃_{t-1}) / s_{t-1}
// so each step needs only ONE global barrier (kernel boundary): read the
// previous step's per-block partials (already written), reduce redundantly
// per block, do the matvec, write sq (unnormalized) + new partials.

#define N 1680
#define NV4 420            // N / 4
#define NBLK 420           // step-kernel blocks, 4 rows (waves) each
#define NSTEP 14

__global__ __launch_bounds__(256) void step_kernel(
    const float* __restrict__ J,
    const float* __restrict__ net_in,        // Iext = net_in[0..N)
    const float* __restrict__ r_prev,        // unnormalized r̃_{t-1} (or r0 at t=0)
    float* __restrict__ r_new,               // r̃_t = sq
    const float* __restrict__ partials_prev, // NBLK partials of s_{t-1} (unused if first)
    float* __restrict__ partials_cur,        // NBLK partials of s_t
    float* __restrict__ d_out,               // U written when last
    int first, int last)
{
    __shared__ float r_lds[N];
    __shared__ float sred[4];
    __shared__ float wsq[4];

    const int tid  = threadIdx.x;
    const int lane = tid & 63;
    const int wave = tid >> 6;

    // Stage r̃_{t-1} into LDS (float4, coalesced).
    const float4* rp4 = (const float4*)r_prev;
    float4* rl4 = (float4*)r_lds;
    for (int i = tid; i < NV4; i += 256) rl4[i] = rp4[i];

    // Redundant per-block reduction of previous step's partials -> s_{t-1}.
    float p = 0.0f;
    if (!first) {
        for (int i = tid; i < NBLK; i += 256) p += partials_prev[i];
    }
    #pragma unroll
    for (int off = 32; off; off >>= 1) p += __shfl_xor(p, off, 64);
    if (lane == 0) sred[wave] = p;
    __syncthreads();   // covers both r_lds staging and sred
    const float s_prev = first ? 1.0f : (sred[0] + sred[1] + sred[2] + sred[3]);

    // One wave per row: dot(J[row,:], r̃_{t-1})
    const int row = blockIdx.x * 4 + wave;
    const float4* Jrow = (const float4*)(J + (size_t)row * N);
    float acc = 0.0f;
    #pragma unroll
    for (int k = 0; k < 7; ++k) {
        const int idx = lane + 64 * k;
        if (idx < NV4) {
            const float4 a = Jrow[idx];
            const float4 b = rl4[idx];
            acc += a.x * b.x + a.y * b.y + a.z * b.z + a.w * b.w;
        }
    }
    #pragma unroll
    for (int off = 32; off; off >>= 1) acc += __shfl_xor(acc, off, 64);

    if (lane == 0) {
        const float U  = acc / s_prev + net_in[row];   // ALPHA=BETA=1
        const float u2 = 0.2f * U;
        const float sq = u2 * u2;
        r_new[row] = sq;                                // unnormalized r̃_t
        if (last) d_out[row] = U;                       // U_13 -> out[0..N)
        wsq[wave] = 0.005f * sq;                        // K * sq
    }
    __syncthreads();
    if (tid == 0) partials_cur[blockIdx.x] = wsq[0] + wsq[1] + wsq[2] + wsq[3];
}

__global__ __launch_bounds__(256) void finish_kernel(
    const float* __restrict__ r_last_un,     // r̃_13 = sq_13
    const float* __restrict__ partials_last, // NBLK partials of s_13
    float* __restrict__ d_out)
{
    __shared__ float sred[4];
    const int tid  = threadIdx.x;
    const int lane = tid & 63;
    const int wave = tid >> 6;

    float p = 0.0f;
    for (int i = tid; i < NBLK; i += 256) p += partials_last[i];
    #pragma unroll
    for (int off = 32; off; off >>= 1) p += __shfl_xor(p, off, 64);
    if (lane == 0) sred[wave] = p;
    __syncthreads();
    const float s = sred[0] + sred[1] + sred[2] + sred[3];

    const int gid = blockIdx.x * 256 + tid;
    if (gid == 0) d_out[N] = s;                        // recSum_13 -> out[N]
    if (gid < N) d_out[N + 1 + gid] = r_last_un[gid] / s;  // r_13 -> out[N+1..]
}

extern "C" void kernel_launch(void* const* d_in, const int* in_sizes, int n_in,
                              void* d_out, int out_size, void* d_ws, size_t ws_size,
                              hipStream_t stream) {
    const float* net_in = (const float*)d_in[0];   // 2N: Iext | r0
    const float* J      = (const float*)d_in[1];   // N x N row-major
    float* out = (float*)d_out;
    float* ws  = (float*)d_ws;

    // ws layout (floats): rbuf0 @0 (1792), rbuf1 @1792, partials @3584 (14*420)
    float* rbuf[2] = { ws, ws + 1792 };
    float* partials = ws + 3584;

    const float* r_prev = net_in + N;   // r0 (16B aligned: 1680*4 % 16 == 0)
    for (int t = 0; t < NSTEP; ++t) {
        float* r_new = rbuf[t & 1];
        const float* pp = (t == 0) ? nullptr : partials + (size_t)(t - 1) * NBLK;
        float* pc = partials + (size_t)t * NBLK;
        step_kernel<<<NBLK, 256, 0, stream>>>(J, net_in, r_prev, r_new, pp, pc,
                                              out, t == 0 ? 1 : 0, t == NSTEP - 1 ? 1 : 0);
        r_prev = r_new;
    }
    finish_kernel<<<7, 256, 0, stream>>>(r_prev, partials + (size_t)(NSTEP - 1) * NBLK, out);
}